// Round 5
// baseline (35.567 us; speedup 1.0000x reference)
//
#include <hip/hip_runtime.h>

#define NB 2
#define C 32
#define H 128
#define W 256
#define D 48
#define HW (H * W)

// ---------------------------------------------------------------------------
// zkern v5: z[n][d][h][w] = sum_c x[n][c][h][w] * y[n][c][h][w-d]  (0 if w<d)
// Grid NB*H*2 (=512 blocks, 2/CU) x 192 threads.
// Same layout as v4 (4w x 8d per thread, 3 ds_read_b128 per c serving 32 FMA)
// plus an explicit 1-deep prefetch of the next c's x float4 so the global
// load's L2/L3 latency overlaps the current c's LDS reads + FMAs.
// ---------------------------------------------------------------------------
__global__ __launch_bounds__(192, 2) void zkern(const float* __restrict__ x,
                                                const float* __restrict__ y,
                                                float* __restrict__ z) {
    const int b    = blockIdx.x;
    const int half = b & 1;
    const int nh   = b >> 1;
    const int n    = nh / H;
    const int h    = nh % H;
    const int tid  = threadIdx.x;
    const int q    = tid & 31;     // w-quad within half: w = 128*half + 4q + o
    const int dg   = tid >> 5;     // 0..5
    const int d0   = dg * 8;

    __shared__ __align__(16) float ys[C][184];   // col <-> y idx ybase+col

    const float* xrow = x + ((size_t)(n * C) * H + h) * (size_t)W;
    const float* yrow = y + ((size_t)(n * C) * H + h) * (size_t)W;
    const int ybase = 128 * half - 48;

    // stage: 32 rows x 46 float4 (zero where y idx OOB; cols>175 never read)
#pragma unroll
    for (int it = 0; it < 8; ++it) {
        const int idx = it * 192 + tid;
        if (idx < 32 * 46) {
            const int r    = idx / 46;
            const int c4   = idx % 46;
            const int yidx = ybase + 4 * c4;
            float4 v = {0.f, 0.f, 0.f, 0.f};
            if (yidx >= 0 && yidx <= W - 4)
                v = *(const float4*)(yrow + (size_t)r * HW + yidx);
            *(float4*)&ys[r][4 * c4] = v;
        }
    }
    __syncthreads();

    float acc[8][4] = {};
    const int S0 = 4 * q + 40 - d0;   // >= 0, 16B-aligned, S0+11 <= 175

    const float* xcol = xrow + 128 * half + 4 * q;
    float4 xv = *(const float4*)xcol;          // c = 0

#pragma unroll
    for (int c = 0; c < C; ++c) {
        float4 xn = xv;
        if (c < C - 1) xn = *(const float4*)(xcol + (size_t)(c + 1) * HW);
        const float4 w0 = *(const float4*)&ys[c][S0];
        const float4 w1 = *(const float4*)&ys[c][S0 + 4];
        const float4 w2 = *(const float4*)&ys[c][S0 + 8];
        const float win[12] = {w0.x, w0.y, w0.z, w0.w,
                               w1.x, w1.y, w1.z, w1.w,
                               w2.x, w2.y, w2.z, w2.w};
        const float xs[4] = {xv.x, xv.y, xv.z, xv.w};
        // acc[k][o] += x[w] * y[w-(d0+k)] ; padded col = 4q+48+o-d -> win[8+o-k]
#pragma unroll
        for (int k = 0; k < 8; ++k)
#pragma unroll
            for (int o = 0; o < 4; ++o)
                acc[k][o] += xs[o] * win[8 + o - k];
        xv = xn;
    }

    float* zp = z + (((size_t)n * D + d0) * H + h) * (size_t)W + 128 * half + 4 * q;
#pragma unroll
    for (int k = 0; k < 8; ++k) {
        float4 v;
        v.x = acc[k][0]; v.y = acc[k][1]; v.z = acc[k][2]; v.w = acc[k][3];
        *(float4*)(zp + (size_t)k * HW) = v;
    }
}

// ---------------------------------------------------------------------------
// fkern v5: out[n][d][h][w] = bias + sum_{i,j} F[n][i*5+j][h][w] *
//                                          z[n][d][h+2(i-2)][w+2(j-2)]
// Parity-pair blocks: block = (n, parity p, pair pi, d-chunk ch of 8).
// Output rows h0 = 4*pi+p and h0+2 share staged z rows: the 6 rows
// hh = h0-4+2l (l=0..5) serve all 10 (row r, tap-row i) combos with r+i=l.
// Each (l, d) window (3 lane-contiguous ds_read_b128) is loaded ONCE and
// reused across the 1-2 (r,i) combos -> 36 b128 per 400 FMA (vs 60 naive).
// zs = 8d x 6l x 264 cols = 50.7 KB -> 3 blocks/CU, 12 waves/CU.
// ---------------------------------------------------------------------------
#define DCH 8
#define NCH (D / DCH)   // 6

__global__ __launch_bounds__(256, 3) void fkern(const float* __restrict__ z,
                                                const float* __restrict__ Ff,
                                                const float* __restrict__ B,
                                                float* __restrict__ out) {
    __shared__ __align__(16) float zs[DCH][6][264];   // col 0 <-> w=-4

    int b = blockIdx.x;
    const int ch = b % NCH;  b /= NCH;   // d-chunk
    const int pi = b % 32;   b /= 32;    // pair index
    const int p  = b % 2;    b /= 2;     // parity
    const int n  = b;                    // batch
    const int h0 = 4 * pi + p;           // output rows h0, h0+2 (both < H)
    const int d0 = ch * DCH;

    const int tid = threadIdx.x;
    const int q   = tid & 63;   // w-quad: w = 4q+o
    const int g   = tid >> 6;   // 0..3 ; owns d = d0+g and d0+g+4

    // stage: 48 rows (8d x 6l) x 66 float4 ; row l <-> hh = h0-4+2l
#pragma unroll
    for (int it = 0; it < 13; ++it) {
        const int idx = it * 256 + tid;
        if (idx < 48 * 66) {
            const int c4 = idx % 66;
            const int t2 = idx / 66;
            const int l  = t2 % 6;
            const int dd = t2 / 6;
            const int hh = h0 - 4 + 2 * l;
            float4 v = {0.f, 0.f, 0.f, 0.f};
            if (c4 >= 1 && c4 <= 64 && hh >= 0 && hh < H)
                v = *(const float4*)(z + (((size_t)n * D + d0 + dd) * H + hh) * (size_t)W
                                       + 4 * c4 - 4);
            *(float4*)&zs[dd][l][4 * c4] = v;
        }
    }

    // bias for the 2 output rows
    float acc[2][2][4];
#pragma unroll
    for (int r = 0; r < 2; ++r) {
        const float4 bv = *(const float4*)(B + ((size_t)n * H + h0 + 2 * r) * (size_t)W + 4 * q);
        acc[r][0][0] = bv.x; acc[r][0][1] = bv.y; acc[r][0][2] = bv.z; acc[r][0][3] = bv.w;
        acc[r][1][0] = bv.x; acc[r][1][1] = bv.y; acc[r][1][2] = bv.z; acc[r][1][3] = bv.w;
    }

    __syncthreads();

#pragma unroll
    for (int l = 0; l < 6; ++l) {
        // two d-windows for this staged row, loaded once, reused across (r,i)
        const float4 a0 = *(const float4*)&zs[g][l][4 * q];
        const float4 a1 = *(const float4*)&zs[g][l][4 * q + 4];
        const float4 a2 = *(const float4*)&zs[g][l][4 * q + 8];
        const float4 b0 = *(const float4*)&zs[g + 4][l][4 * q];
        const float4 b1 = *(const float4*)&zs[g + 4][l][4 * q + 4];
        const float4 b2 = *(const float4*)&zs[g + 4][l][4 * q + 8];
        const float win0[12] = {a0.x, a0.y, a0.z, a0.w, a1.x, a1.y, a1.z, a1.w,
                                a2.x, a2.y, a2.z, a2.w};
        const float win1[12] = {b0.x, b0.y, b0.z, b0.w, b1.x, b1.y, b1.z, b1.w,
                                b2.x, b2.y, b2.z, b2.w};

#pragma unroll
        for (int r = 0; r < 2; ++r) {
            const int i = l - r;               // z row l feeds tap-row i of output r
            if (i < 0 || i > 4) continue;      // compile-time prune
#pragma unroll
            for (int jj = 0; jj < 5; ++jj) {
                const float4 tp = *(const float4*)(Ff + (((size_t)n * 25 + i * 5 + jj) * H
                                                         + h0 + 2 * r) * (size_t)W + 4 * q);
                const float ts[4] = {tp.x, tp.y, tp.z, tp.w};
                // out[w=4q+o] += f * z[d][hh][w+2jj-4] ; padded col 4q+o+2jj
#pragma unroll
                for (int o = 0; o < 4; ++o) {
                    acc[r][0][o] += ts[o] * win0[o + 2 * jj];
                    acc[r][1][o] += ts[o] * win1[o + 2 * jj];
                }
            }
        }
    }

#pragma unroll
    for (int r = 0; r < 2; ++r)
#pragma unroll
        for (int kd = 0; kd < 2; ++kd) {
            float* op = out + (((size_t)n * D + d0 + g + 4 * kd) * H + h0 + 2 * r) * (size_t)W
                            + 4 * q;
            float4 v;
            v.x = acc[r][kd][0]; v.y = acc[r][kd][1];
            v.z = acc[r][kd][2]; v.w = acc[r][kd][3];
            *(float4*)op = v;
        }
}

// ---------------------------------------------------------------------------
// Fallback (workspace too small): fully fused naive version. Correctness only.
// ---------------------------------------------------------------------------
__global__ __launch_bounds__(256) void fused_naive(const float* __restrict__ x,
                                                   const float* __restrict__ y,
                                                   const float* __restrict__ Ff,
                                                   const float* __restrict__ B,
                                                   float* __restrict__ out) {
    const size_t idx = (size_t)blockIdx.x * 256 + threadIdx.x;
    if (idx >= (size_t)NB * D * H * W) return;
    const int w = (int)(idx % W);
    const int h = (int)((idx / W) % H);
    const int d = (int)((idx / ((size_t)W * H)) % D);
    const int n = (int)(idx / ((size_t)W * H * D));

    float acc = B[((size_t)n * H + h) * W + w];
#pragma unroll
    for (int i = 0; i < 5; ++i) {
        const int hh = h + 2 * i - 4;
        if (hh < 0 || hh >= H) continue;
#pragma unroll
        for (int j = 0; j < 5; ++j) {
            const int ww = w + 2 * j - 4;
            if (ww < 0 || ww >= W) continue;
            const int ws_ = ww - d;
            float zv = 0.f;
            if (ws_ >= 0) {
                const float* xp = x + (((size_t)n * C) * H + hh) * (size_t)W + ww;
                const float* yp = y + (((size_t)n * C) * H + hh) * (size_t)W + ws_;
                for (int c = 0; c < C; ++c)
                    zv += xp[(size_t)c * HW] * yp[(size_t)c * HW];
            }
            acc += Ff[(((size_t)n * 25 + i * 5 + j) * H + h) * (size_t)W + w] * zv;
        }
    }
    out[idx] = acc;
}

extern "C" void kernel_launch(void* const* d_in, const int* in_sizes, int n_in,
                              void* d_out, int out_size, void* d_ws, size_t ws_size,
                              hipStream_t stream) {
    const float* x = (const float*)d_in[0];
    const float* y = (const float*)d_in[1];
    const float* F = (const float*)d_in[2];
    const float* B = (const float*)d_in[3];
    float* out = (float*)d_out;

    const size_t zbytes = (size_t)NB * D * H * W * sizeof(float);

    if (ws_size >= zbytes) {
        float* z = (float*)d_ws;
        zkern<<<NB * H * 2, 192, 0, stream>>>(x, y, z);
        fkern<<<NB * 2 * 32 * NCH, 256, 0, stream>>>(z, F, B, out);
    } else {
        const size_t total = (size_t)NB * D * H * W;
        fused_naive<<<(int)((total + 255) / 256), 256, 0, stream>>>(x, y, F, B, out);
    }
}